// Round 8
// baseline (806.950 us; speedup 1.0000x reference)
//
#include <hip/hip_runtime.h>

// GcnEncoderGraph as ONE dataflow kernel (plus a 512B memset for flags).
// B=8, N=2048, DIN=32, DH=DE=64, R=3.
// R8: grid=256=#CUs (full residency guaranteed -> no deadlock), block
// (b=bid&7 -> XCD-affine, it=bid>>3). Phases chained by per-b / per-it
// device-scope counters (release-fence+bump / spin+acquire-fence) instead of
// dispatch boundaries (~15us each, 7x) or cg grid.sync (~97us, R4).
// relation is bit-packed directly into LDS (never hits global); union plane
// (XOR-swizzled, conflict-free) persists for layers 2/3. Same-b XWS slabs
// stay in one XCD's L2. Phase bodies = R7-proven code re-mapped to 512 thr.

#define NN 2048

typedef short short8 __attribute__((ext_vector_type(8)));
typedef float floatx4 __attribute__((ext_vector_type(4)));

__device__ __forceinline__ unsigned short f2bf(float x) {
  unsigned u = __float_as_uint(x);
  u += 0x7FFFu + ((u >> 16) & 1u);
  return (unsigned short)(u >> 16);
}

__device__ __forceinline__ float bf2f(unsigned short v) {
  return __uint_as_float(((unsigned)v) << 16);
}

__device__ __forceinline__ void bump(unsigned* c) {
  __threadfence();   // release: make this block's global writes visible
  __syncthreads();
  if (threadIdx.x == 0)
    __hip_atomic_fetch_add(c, 1u, __ATOMIC_RELEASE, __HIP_MEMORY_SCOPE_AGENT);
}

__device__ __forceinline__ void waitc(unsigned* c, unsigned tgt) {
  if (threadIdx.x == 0) {
    while (__hip_atomic_load(c, __ATOMIC_RELAXED, __HIP_MEMORY_SCOPE_AGENT) < tgt)
      __builtin_amdgcn_s_sleep(1);
  }
  __syncthreads();
  __threadfence();   // acquire: invalidate stale cached lines before reads
}

// ---------- masked MFMA gemm phase (R7 k_gemm8 core, full-K from LDS masks) --
// mloc: LDS mask planes [NREL][64 rows][64 words], word w of row at
// row*64 + (w ^ (row&31)) (XOR swizzle, conflict-free). scratch: 16KB combine.
template <int NREL, bool RELU, bool POOL3>
__device__ void gemm_phase(const unsigned* __restrict__ mloc, char* scratch,
                           const unsigned short* __restrict__ xwsL,
                           const float* __restrict__ bias,
                           float* __restrict__ Hout, float* __restrict__ part3,
                           int b, int it) {
  const int tid = threadIdx.x;
  const int wave = tid >> 6, lane = tid & 63;
  const int m = lane & 15, kq = lane >> 4;
  const int i0 = it * 64;

  floatx4 acc[4][4];
#pragma unroll
  for (int rs = 0; rs < 4; ++rs)
#pragma unroll
    for (int t = 0; t < 4; ++t) acc[rs][t] = floatx4{0, 0, 0, 0};

  for (int kk8 = 0; kk8 < 8; ++kk8) {
    const int kblk = kk8 * 8 + wave;
#pragma unroll
    for (int p = 0; p < NREL; ++p) {
      const unsigned short* bb2 =
          xwsL + ((long)(p * 8 + b) * 64 + kblk) * 2048 + lane * 8;
      short8 bf0 = *(const short8*)(bb2);
      short8 bf1 = *(const short8*)(bb2 + 512);
      short8 bf2 = *(const short8*)(bb2 + 1024);
      short8 bf3 = *(const short8*)(bb2 + 1536);
#pragma unroll
      for (int rs = 0; rs < 4; ++rs) {
        const int row = rs * 16 + m;
        unsigned word = mloc[p * 4096 + row * 64 + (kblk ^ (row & 31))];
        unsigned byte = (word >> (kq * 8)) & 0xffu;
        unsigned pp = byte | (byte << 15);
        union {
          unsigned uu[4];
          short8 s8;
        } fr;
        unsigned w0 = pp & 0x00010001u;
        fr.uu[0] = (w0 << 14) - (w0 << 7);  // bf16 1.0 = (b<<14)-(b<<7)
        unsigned w1 = pp & 0x00040004u;
        fr.uu[1] = (w1 << 12) - (w1 << 5);
        unsigned w2 = pp & 0x00100010u;
        fr.uu[2] = (w2 << 10) - (w2 << 3);
        unsigned w3 = pp & 0x00400040u;
        fr.uu[3] = (w3 << 8) - (w3 << 1);
        acc[rs][0] = __builtin_amdgcn_mfma_f32_16x16x32_bf16(fr.s8, bf0,
                                                             acc[rs][0], 0, 0, 0);
        acc[rs][1] = __builtin_amdgcn_mfma_f32_16x16x32_bf16(fr.s8, bf1,
                                                             acc[rs][1], 0, 0, 0);
        acc[rs][2] = __builtin_amdgcn_mfma_f32_16x16x32_bf16(fr.s8, bf2,
                                                             acc[rs][2], 0, 0, 0);
        acc[rs][3] = __builtin_amdgcn_mfma_f32_16x16x32_bf16(fr.s8, bf3,
                                                             acc[rs][3], 0, 0, 0);
      }
    }
  }
  __syncthreads();  // masks (or prior scratch) dead; scratch = combine buffer
  floatx4* cb = (floatx4*)scratch;
  for (int k = 7; k >= 1; --k) {
    if (wave == k) {
      if (k == 7) {
#pragma unroll
        for (int rs = 0; rs < 4; ++rs)
#pragma unroll
          for (int t = 0; t < 4; ++t) cb[(rs * 4 + t) * 64 + lane] = acc[rs][t];
      } else {
#pragma unroll
        for (int rs = 0; rs < 4; ++rs)
#pragma unroll
          for (int t = 0; t < 4; ++t) {
            floatx4 v = cb[(rs * 4 + t) * 64 + lane];
            cb[(rs * 4 + t) * 64 + lane] = v + acc[rs][t];
          }
      }
    }
    __syncthreads();
  }
  if (wave == 0) {
#pragma unroll
    for (int rs = 0; rs < 4; ++rs)
#pragma unroll
      for (int t = 0; t < 4; ++t) acc[rs][t] += cb[(rs * 4 + t) * 64 + lane];
    float bv[4];
#pragma unroll
    for (int t = 0; t < 4; ++t) bv[t] = bias[t * 16 + m];
    float pmt[4] = {-3.4e38f, -3.4e38f, -3.4e38f, -3.4e38f};
#pragma unroll
    for (int rs = 0; rs < 4; ++rs) {
      float ss[4];
#pragma unroll
      for (int reg = 0; reg < 4; ++reg) {
#pragma unroll
        for (int t = 0; t < 4; ++t) acc[rs][t][reg] += bv[t];
        ss[reg] = acc[rs][0][reg] * acc[rs][0][reg] +
                  acc[rs][1][reg] * acc[rs][1][reg] +
                  acc[rs][2][reg] * acc[rs][2][reg] +
                  acc[rs][3][reg] * acc[rs][3][reg];
#pragma unroll
        for (int off = 1; off <= 8; off <<= 1)
          ss[reg] += __shfl_xor(ss[reg], off);
        ss[reg] = 1.0f / fmaxf(sqrtf(ss[reg]), 1e-12f);
      }
#pragma unroll
      for (int t = 0; t < 4; ++t) {
#pragma unroll
        for (int reg = 0; reg < 4; ++reg) {
          float o = acc[rs][t][reg] * ss[reg];
          if (RELU) o = fmaxf(o, 0.0f);
          if (POOL3)
            pmt[t] = fmaxf(pmt[t], o);
          else
            Hout[((long)b * NN + i0 + rs * 16 + kq * 4 + reg) * 64 + t * 16 + m] = o;
        }
      }
    }
    if (POOL3) {
#pragma unroll
      for (int t = 0; t < 4; ++t) {
        pmt[t] = fmaxf(pmt[t], __shfl_xor(pmt[t], 16));
        pmt[t] = fmaxf(pmt[t], __shfl_xor(pmt[t], 32));
      }
      if (kq == 0) {
#pragma unroll
        for (int t = 0; t < 4; ++t)
          part3[((long)b * 32 + it) * 64 + t * 16 + m] = pmt[t];
      }
    }
  }
}

// ---------- BN + XW phase (R7 k_xwh_bn re-mapped to 512 threads) -------------
__device__ void bnxw_phase(char* scratch, const float* __restrict__ Hsrc,
                           const float* __restrict__ wmat,
                           unsigned short* __restrict__ xwsD,
                           float* __restrict__ PPdst, int b, int it) {
  float* hs = (float*)scratch;                // [64][65] 16640B
  float* wsh = (float*)(scratch + 16640);     // [64][64] 16384B
  float* smean = (float*)(scratch + 33024);   // 64
  float* srsv = (float*)(scratch + 33280);    // 64
  const int tid = threadIdx.x;
  const int i0 = it * 64;
  {  // stats: thread = (node n = tid>>3, batch s = tid&7), 64 e each
    const int n = tid >> 3, s = tid & 7;
    const float4* hp = (const float4*)(Hsrc + ((long)s * NN + i0 + n) * 64);
    float s1 = 0.f, s2 = 0.f;
#pragma unroll
    for (int c = 0; c < 16; ++c) {
      float4 v = hp[c];
      s1 += v.x + v.y + v.z + v.w;
      s2 += v.x * v.x + v.y * v.y + v.z * v.z + v.w * v.w;
    }
    s1 += __shfl_xor(s1, 1); s2 += __shfl_xor(s2, 1);
    s1 += __shfl_xor(s1, 2); s2 += __shfl_xor(s2, 2);
    s1 += __shfl_xor(s1, 4); s2 += __shfl_xor(s2, 4);
    if (s == 0) {
      float mean = s1 * (1.0f / 512.0f);
      float var = fmaxf(s2 * (1.0f / 512.0f) - mean * mean, 0.0f);
      smean[n] = mean;
      srsv[n] = rsqrtf(var + 1e-5f);
    }
  }
  __syncthreads();
  for (int idx = tid; idx < 4096; idx += 512) {
    int row = idx >> 6, f = idx & 63;
    float v = Hsrc[((long)b * NN + i0 + row) * 64 + f];
    hs[row * 65 + f] = (v - smean[row]) * srsv[row];
    wsh[idx] = wmat[idx];
  }
  __syncthreads();
  {  // xw: thread = (node j = tid&63, e-group gg = tid>>6), 8 e each
    const int j = tid & 63, gg = tid >> 6;
    const int k = i0 + j;
    const int kblk = k >> 5, kqq = (k >> 3) & 3, kj = k & 7;
    float xr[64];
#pragma unroll
    for (int f = 0; f < 64; ++f) xr[f] = hs[j * 65 + f];
#pragma unroll
    for (int ii = 0; ii < 8; ++ii) {
      const int e = gg * 8 + ii;
      float a = 0.f;
#pragma unroll
      for (int f = 0; f < 64; ++f) a += xr[f] * wsh[f * 64 + e];
      xwsD[(((long)b * 64 + kblk) * 4 + (e >> 4)) * 512 +
           (kqq * 16 + (e & 15)) * 8 + kj] = f2bf(a);
    }
  }
  if (b == 0) {  // pool partials over this node-tile, all (bb,e)
    const int bb = tid >> 6, e = tid & 63;
    float mx = -3.4e38f;
    for (int n = 0; n < 64; ++n) {
      float v = Hsrc[((long)bb * NN + i0 + n) * 64 + e];
      mx = fmaxf(mx, (v - smean[n]) * srsv[n]);
    }
    PPdst[(long)it * 512 + tid] = mx;
  }
}

// ---------------- the dataflow kernel ----------------------------------------
__global__ __launch_bounds__(512, 2) void gcn_df(
    const float* __restrict__ x, const int* __restrict__ rel,
    const float* __restrict__ w_first, const float* __restrict__ b_first,
    const float* __restrict__ w_block, const float* __restrict__ b_block,
    const float* __restrict__ w_last, const float* __restrict__ b_last,
    const float* __restrict__ w_map, const float* __restrict__ b_map,
    float* __restrict__ out, unsigned short* __restrict__ XWS1,
    unsigned short* __restrict__ XWS2, unsigned short* __restrict__ XWS3,
    float* __restrict__ H1, float* __restrict__ H2, float* __restrict__ PP1,
    float* __restrict__ PP2, float* __restrict__ PART3,
    unsigned* __restrict__ cnt) {
  __shared__ __align__(16) char smem[65536];
  unsigned* uplane = (unsigned*)smem;  // 16KB persistent union plane
  char* scratch = smem + 16384;        // 48KB phase scratch
  const int bid = blockIdx.x, tid = threadIdx.x;
  const int b = bid & 7, it = bid >> 3;  // XCD = bid%8 = b
  const int i0 = it * 64;

  // ---- P1a: XW layer1 for this node-tile (scratch: xs + wsh) ----
  {
    float* xs = (float*)scratch;             // [64][33]
    float* wsh = (float*)(scratch + 8448);   // [32][64]
    for (int idx = tid; idx < 2048; idx += 512) {
      int row = idx >> 5, f = idx & 31;
      xs[row * 33 + f] = x[((long)b * NN + i0 + row) * 32 + f];
    }
    __syncthreads();
    const int j = tid & 63, gg = tid >> 6;
    const int k = i0 + j;
    const int kblk = k >> 5, kqq = (k >> 3) & 3, kj = k & 7;
    float xr[32];
#pragma unroll
    for (int f = 0; f < 32; ++f) xr[f] = xs[j * 33 + f];
    for (int r = 0; r < 3; ++r) {
      for (int idx = tid; idx < 2048; idx += 512) wsh[idx] = w_first[r * 2048 + idx];
      __syncthreads();
#pragma unroll
      for (int ii = 0; ii < 8; ++ii) {
        const int e = gg * 8 + ii;
        float a = 0.f;
#pragma unroll
        for (int f = 0; f < 32; ++f) a += xr[f] * wsh[f * 64 + e];
        XWS1[(((long)(r * 8 + b) * 64 + kblk) * 4 + (e >> 4)) * 512 +
             (kqq * 16 + (e & 15)) * 8 + kj] = f2bf(a);
      }
      __syncthreads();
    }
  }
  // ---- P1b: pack relation rows of this tile into LDS (never to global) ----
  {
    unsigned* mw3 = (unsigned*)scratch;  // [3][64][64] swizzled, 48KB
    const int row = tid >> 3, seg = tid & 7;
    const int rsw = row & 31;
    const long base = ((long)b * NN + i0 + row) * NN + seg * 256;
#pragma unroll
    for (int w8 = 0; w8 < 8; ++w8) {
      const int w = seg * 8 + w8;
      const int4* rp = (const int4*)(rel + base + w8 * 32);
      unsigned m0 = 0, m1 = 0, m2 = 0;
#pragma unroll
      for (int c = 0; c < 8; ++c) {
        int4 v = rp[c];
        int vv[4] = {v.x, v.y, v.z, v.w};
#pragma unroll
        for (int q = 0; q < 4; ++q) {
          unsigned bit = 1u << (c * 4 + q);
          m0 |= (vv[q] == 1) ? bit : 0u;
          m1 |= (vv[q] == 2) ? bit : 0u;
          m2 |= (vv[q] == 3) ? bit : 0u;
        }
      }
      const int off = row * 64 + (w ^ rsw);
      mw3[off] = m0;
      mw3[4096 + off] = m1;
      mw3[8192 + off] = m2;
      uplane[off] = m0 | m1 | m2;
    }
  }
  bump(&cnt[b]);  // A: XWS1 slab + (LDS masks are local)

  // ---- P2: gemm layer1 (3 planes from LDS) ----
  waitc(&cnt[b], 32);
  gemm_phase<3, true, false>((unsigned*)scratch, scratch, XWS1, b_first, H1,
                             nullptr, b, it);
  bump(&cnt[8 + it]);  // B: H1 tile

  // ---- P3: BN1 + XW layer2 (+PP1 partials from b==0) ----
  waitc(&cnt[8 + it], 8);
  bnxw_phase(scratch, H1, w_block, XWS2, PP1, b, it);
  bump(&cnt[40 + b]);  // C: XWS2 slab

  // ---- P4: gemm layer2 (union plane) ----
  waitc(&cnt[40 + b], 32);
  gemm_phase<1, true, false>(uplane, scratch, XWS2, b_block, H2, nullptr, b, it);
  bump(&cnt[48 + it]);  // D: H2 tile

  // ---- P5: BN2 + XW layer3 (+PP2) ----
  waitc(&cnt[48 + it], 8);
  bnxw_phase(scratch, H2, w_last, XWS3, PP2, b, it);
  bump(&cnt[80 + b]);  // E: XWS3 slab

  // ---- P6: gemm layer3 (union plane, L2norm only, pool3 partial) ----
  waitc(&cnt[80 + b], 32);
  gemm_phase<1, false, true>(uplane, scratch, XWS3, b_last, nullptr, PART3, b, it);
  bump(&cnt[88]);  // F: all done

  // ---- P7: tail (block 0): pool finals + linear head ----
  if (bid == 0) {
    waitc(&cnt[88], 256);
    const int bb = tid >> 6, e = tid & 63;
    float m1 = -3.4e38f, m2 = -3.4e38f, m3 = -3.4e38f;
#pragma unroll
    for (int c = 0; c < 32; ++c) {
      m1 = fmaxf(m1, PP1[(long)c * 512 + tid]);
      m2 = fmaxf(m2, PP2[(long)c * 512 + tid]);
      m3 = fmaxf(m3, PART3[((long)bb * 32 + c) * 64 + e]);
    }
    out[bb * 192 + e] = m1;
    out[bb * 192 + 64 + e] = m2;
    out[bb * 192 + 128 + e] = m3;
    __syncthreads();
    float a = b_map[e];
    for (int k = 0; k < 192; ++k) a += out[bb * 192 + k] * w_map[k * 64 + e];
    out[1536 + bb * 64 + e] = a;
  }
}

extern "C" void kernel_launch(void* const* d_in, const int* in_sizes, int n_in,
                              void* d_out, int out_size, void* d_ws,
                              size_t ws_size, hipStream_t stream) {
  const float* x = (const float*)d_in[0];
  const int* rel = (const int*)d_in[1];
  // d_in[2] (adj) unread: adj == (rel > 0) == union of bit-planes
  const float* w_first = (const float*)d_in[3];
  const float* b_first = (const float*)d_in[4];
  const float* w_block = (const float*)d_in[5];
  const float* b_block = (const float*)d_in[6];
  const float* w_last = (const float*)d_in[7];
  const float* b_last = (const float*)d_in[8];
  const float* w_map = (const float*)d_in[9];
  const float* b_map = (const float*)d_in[10];
  float* out = (float*)d_out;

  char* ws = (char*)d_ws;
  const size_t MB = 1024 * 1024;
  unsigned short* XWS1 = (unsigned short*)(ws);            // 6 MiB
  unsigned short* XWS2 = (unsigned short*)(ws + 6 * MB);   // 2 MiB
  unsigned short* XWS3 = (unsigned short*)(ws + 8 * MB);   // 2 MiB
  float* H1 = (float*)(ws + 10 * MB);                      // 4 MiB
  float* H2 = (float*)(ws + 14 * MB);                      // 4 MiB
  float* PP1 = (float*)(ws + 18 * MB);                     // 64 KiB
  float* PP2 = (float*)(ws + 19 * MB);                     // 64 KiB
  float* PART3 = (float*)(ws + 20 * MB);                   // 64 KiB
  unsigned* CNT = (unsigned*)(ws + 21 * MB);               // 512 B

  hipMemsetAsync((void*)CNT, 0, 512, stream);
  gcn_df<<<256, 512, 0, stream>>>(x, rel, w_first, b_first, w_block, b_block,
                                  w_last, b_last, w_map, b_map, out, XWS1,
                                  XWS2, XWS3, H1, H2, PP1, PP2, PART3, CNT);
}

// Round 9
// 751.550 us; speedup vs baseline: 1.0737x; 1.0737x over previous
//
#include <hip/hip_runtime.h>

// GcnEncoderGraph, 5 graph nodes: memset + xw1 + 3 fused gemm kernels.
// B=8, N=2048, DIN=32, DH=DE=64, R=3.
// R9: R7 multi-kernel core (353us) + non-blocking "last-arriver" fusion
// (R8-validated fence/atomic protocol, but NO spins): gemm1 reads `rel`
// directly (pack kernel deleted; union plane emitted as side product);
// the 8th block per node-tile does BN+XW-next inline; last block of gemm3
// does pool finals + pred. All-block rendezvous (cg.sync ~97us, spin ~70us/
// round, R4/R8) permanently abandoned.

#define NN 2048

typedef short short8 __attribute__((ext_vector_type(8)));
typedef float floatx4 __attribute__((ext_vector_type(4)));

__device__ __forceinline__ unsigned short f2bf(float x) {
  unsigned u = __float_as_uint(x);
  u += 0x7FFFu + ((u >> 16) & 1u);
  return (unsigned short)(u >> 16);
}

// ---------- masked MFMA gemm core (R8-proven, 8 waves, full K) ---------------
// mloc: LDS masks [NREL][64 rows][64 words], word w at row*64 + (w^(row&31)).
// scratch: combine buffer (overlays masks after internal barrier).
template <int NREL, bool RELU, bool POOL3>
__device__ void gemm_core(const unsigned* __restrict__ mloc, char* scratch,
                          const unsigned short* __restrict__ xwsL,
                          const float* __restrict__ bias,
                          float* __restrict__ Hout, float* __restrict__ part3,
                          int b, int it) {
  const int tid = threadIdx.x;
  const int wave = tid >> 6, lane = tid & 63;
  const int m = lane & 15, kq = lane >> 4;
  const int i0 = it * 64;

  floatx4 acc[4][4];
#pragma unroll
  for (int rs = 0; rs < 4; ++rs)
#pragma unroll
    for (int t = 0; t < 4; ++t) acc[rs][t] = floatx4{0, 0, 0, 0};

  for (int kk8 = 0; kk8 < 8; ++kk8) {
    const int kblk = kk8 * 8 + wave;
#pragma unroll
    for (int p = 0; p < NREL; ++p) {
      const unsigned short* bb2 =
          xwsL + ((long)(p * 8 + b) * 64 + kblk) * 2048 + lane * 8;
      short8 bf0 = *(const short8*)(bb2);
      short8 bf1 = *(const short8*)(bb2 + 512);
      short8 bf2 = *(const short8*)(bb2 + 1024);
      short8 bf3 = *(const short8*)(bb2 + 1536);
#pragma unroll
      for (int rs = 0; rs < 4; ++rs) {
        const int row = rs * 16 + m;
        unsigned word = mloc[p * 4096 + row * 64 + (kblk ^ (row & 31))];
        unsigned byte = (word >> (kq * 8)) & 0xffu;
        unsigned pp = byte | (byte << 15);
        union {
          unsigned uu[4];
          short8 s8;
        } fr;
        unsigned w0 = pp & 0x00010001u;
        fr.uu[0] = (w0 << 14) - (w0 << 7);  // bf16 1.0 = (b<<14)-(b<<7)
        unsigned w1 = pp & 0x00040004u;
        fr.uu[1] = (w1 << 12) - (w1 << 5);
        unsigned w2 = pp & 0x00100010u;
        fr.uu[2] = (w2 << 10) - (w2 << 3);
        unsigned w3 = pp & 0x00400040u;
        fr.uu[3] = (w3 << 8) - (w3 << 1);
        acc[rs][0] = __builtin_amdgcn_mfma_f32_16x16x32_bf16(fr.s8, bf0,
                                                             acc[rs][0], 0, 0, 0);
        acc[rs][1] = __builtin_amdgcn_mfma_f32_16x16x32_bf16(fr.s8, bf1,
                                                             acc[rs][1], 0, 0, 0);
        acc[rs][2] = __builtin_amdgcn_mfma_f32_16x16x32_bf16(fr.s8, bf2,
                                                             acc[rs][2], 0, 0, 0);
        acc[rs][3] = __builtin_amdgcn_mfma_f32_16x16x32_bf16(fr.s8, bf3,
                                                             acc[rs][3], 0, 0, 0);
      }
    }
  }
  __syncthreads();  // masks dead; scratch = combine buffer
  floatx4* cb = (floatx4*)scratch;
  for (int k = 7; k >= 1; --k) {
    if (wave == k) {
      if (k == 7) {
#pragma unroll
        for (int rs = 0; rs < 4; ++rs)
#pragma unroll
          for (int t = 0; t < 4; ++t) cb[(rs * 4 + t) * 64 + lane] = acc[rs][t];
      } else {
#pragma unroll
        for (int rs = 0; rs < 4; ++rs)
#pragma unroll
          for (int t = 0; t < 4; ++t) {
            floatx4 v = cb[(rs * 4 + t) * 64 + lane];
            cb[(rs * 4 + t) * 64 + lane] = v + acc[rs][t];
          }
      }
    }
    __syncthreads();
  }
  if (wave == 0) {
#pragma unroll
    for (int rs = 0; rs < 4; ++rs)
#pragma unroll
      for (int t = 0; t < 4; ++t) acc[rs][t] += cb[(rs * 4 + t) * 64 + lane];
    float bv[4];
#pragma unroll
    for (int t = 0; t < 4; ++t) bv[t] = bias[t * 16 + m];
    float pmt[4] = {-3.4e38f, -3.4e38f, -3.4e38f, -3.4e38f};
#pragma unroll
    for (int rs = 0; rs < 4; ++rs) {
      float ss[4];
#pragma unroll
      for (int reg = 0; reg < 4; ++reg) {
#pragma unroll
        for (int t = 0; t < 4; ++t) acc[rs][t][reg] += bv[t];
        ss[reg] = acc[rs][0][reg] * acc[rs][0][reg] +
                  acc[rs][1][reg] * acc[rs][1][reg] +
                  acc[rs][2][reg] * acc[rs][2][reg] +
                  acc[rs][3][reg] * acc[rs][3][reg];
#pragma unroll
        for (int off = 1; off <= 8; off <<= 1)
          ss[reg] += __shfl_xor(ss[reg], off);
        ss[reg] = 1.0f / fmaxf(sqrtf(ss[reg]), 1e-12f);
      }
#pragma unroll
      for (int t = 0; t < 4; ++t) {
#pragma unroll
        for (int reg = 0; reg < 4; ++reg) {
          float o = acc[rs][t][reg] * ss[reg];
          if (RELU) o = fmaxf(o, 0.0f);
          if (POOL3)
            pmt[t] = fmaxf(pmt[t], o);
          else
            Hout[((long)b * NN + i0 + rs * 16 + kq * 4 + reg) * 64 + t * 16 + m] = o;
        }
      }
    }
    if (POOL3) {
#pragma unroll
      for (int t = 0; t < 4; ++t) {
        pmt[t] = fmaxf(pmt[t], __shfl_xor(pmt[t], 16));
        pmt[t] = fmaxf(pmt[t], __shfl_xor(pmt[t], 32));
      }
      if (kq == 0) {
#pragma unroll
        for (int t = 0; t < 4; ++t)
          part3[((long)b * 32 + it) * 64 + t * 16 + m] = pmt[t];
      }
    }
  }
}

// ---------- BN (+pool partials) + XW-next for node-tile `it`, all 8 batches --
__device__ void bnxw_all(char* scratch, const float* __restrict__ Hsrc,
                         const float* __restrict__ wmat,
                         unsigned short* __restrict__ xwsD,
                         float* __restrict__ PPdst, int it) {
  float* hs = (float*)scratch;               // [64][65]
  float* wsh = (float*)(scratch + 16640);    // [64][64]
  float* smean = (float*)(scratch + 33024);  // 64
  float* srsv = (float*)(scratch + 33280);   // 64
  const int tid = threadIdx.x;
  const int i0 = it * 64;
  {  // stats: thread = (node n = tid>>3, batch s = tid&7) [R8-proven]
    const int n = tid >> 3, s = tid & 7;
    const float4* hp = (const float4*)(Hsrc + ((long)s * NN + i0 + n) * 64);
    float s1 = 0.f, s2 = 0.f;
#pragma unroll
    for (int c = 0; c < 16; ++c) {
      float4 v = hp[c];
      s1 += v.x + v.y + v.z + v.w;
      s2 += v.x * v.x + v.y * v.y + v.z * v.z + v.w * v.w;
    }
    s1 += __shfl_xor(s1, 1); s2 += __shfl_xor(s2, 1);
    s1 += __shfl_xor(s1, 2); s2 += __shfl_xor(s2, 2);
    s1 += __shfl_xor(s1, 4); s2 += __shfl_xor(s2, 4);
    if (s == 0) {
      float mean = s1 * (1.0f / 512.0f);
      float var = fmaxf(s2 * (1.0f / 512.0f) - mean * mean, 0.0f);
      smean[n] = mean;
      srsv[n] = rsqrtf(var + 1e-5f);
    }
  }
  __syncthreads();
  for (int idx = tid; idx < 4096; idx += 512) wsh[idx] = wmat[idx];
  {  // pool partials for this node tile, all (bb,e)
    const int bb = tid >> 6, e = tid & 63;
    float mx = -3.4e38f;
    for (int n = 0; n < 64; ++n) {
      float v = Hsrc[((long)bb * NN + i0 + n) * 64 + e];
      mx = fmaxf(mx, (v - smean[n]) * srsv[n]);
    }
    PPdst[(long)it * 512 + tid] = mx;
  }
  for (int bb = 0; bb < 8; ++bb) {
    __syncthreads();
    for (int idx = tid; idx < 4096; idx += 512) {
      int row = idx >> 6, f = idx & 63;
      float v = Hsrc[((long)bb * NN + i0 + row) * 64 + f];
      hs[row * 65 + f] = (v - smean[row]) * srsv[row];
    }
    __syncthreads();
    const int j = tid & 63, gg = tid >> 6;
    const int k = i0 + j;
    const int kblk = k >> 5, kqq = (k >> 3) & 3, kj = k & 7;
    float xr[64];
#pragma unroll
    for (int f = 0; f < 64; ++f) xr[f] = hs[j * 65 + f];
#pragma unroll
    for (int ii = 0; ii < 8; ++ii) {
      const int e = gg * 8 + ii;
      float a = 0.f;
#pragma unroll
      for (int f = 0; f < 64; ++f) a += xr[f] * wsh[f * 64 + e];
      xwsD[(((long)bb * 64 + kblk) * 4 + (e >> 4)) * 512 +
           (kqq * 16 + (e & 15)) * 8 + kj] = f2bf(a);
    }
  }
}

// ---------- last-arriver helper (release fence + bump; no spin) --------------
__device__ __forceinline__ bool last_arriver(unsigned* c, unsigned n,
                                             unsigned* lastf_s) {
  __threadfence();
  __syncthreads();
  if (threadIdx.x == 0) {
    unsigned r = __hip_atomic_fetch_add(c, 1u, __ATOMIC_ACQ_REL,
                                        __HIP_MEMORY_SCOPE_AGENT);
    *lastf_s = (r == n - 1) ? 1u : 0u;
  }
  __syncthreads();
  if (*lastf_s) {
    __threadfence();  // acquire: see other blocks' writes
    return true;
  }
  return false;
}

// ---------- k_xw1: XW layer1, swizzled (R8 P1a verbatim) ---------------------
__global__ __launch_bounds__(512, 2) void k_xw1(const float* __restrict__ x,
                                                const float* __restrict__ w_first,
                                                unsigned short* __restrict__ XWS1) {
  __shared__ __align__(16) char smem[16640];
  const int bid = blockIdx.x, tid = threadIdx.x;
  const int b = bid & 7, it = bid >> 3;
  const int i0 = it * 64;
  float* xs = (float*)smem;            // [64][33]
  float* wsh = (float*)(smem + 8448);  // [32][64]
  for (int idx = tid; idx < 2048; idx += 512) {
    int row = idx >> 5, f = idx & 31;
    xs[row * 33 + f] = x[((long)b * NN + i0 + row) * 32 + f];
  }
  __syncthreads();
  const int j = tid & 63, gg = tid >> 6;
  const int k = i0 + j;
  const int kblk = k >> 5, kqq = (k >> 3) & 3, kj = k & 7;
  float xr[32];
#pragma unroll
  for (int f = 0; f < 32; ++f) xr[f] = xs[j * 33 + f];
  for (int r = 0; r < 3; ++r) {
    for (int idx = tid; idx < 2048; idx += 512) wsh[idx] = w_first[r * 2048 + idx];
    __syncthreads();
#pragma unroll
    for (int ii = 0; ii < 8; ++ii) {
      const int e = gg * 8 + ii;
      float a = 0.f;
#pragma unroll
      for (int f = 0; f < 32; ++f) a += xr[f] * wsh[f * 64 + e];
      XWS1[(((long)(r * 8 + b) * 64 + kblk) * 4 + (e >> 4)) * 512 +
           (kqq * 16 + (e & 15)) * 8 + kj] = f2bf(a);
    }
    __syncthreads();
  }
}

// ---------- k_g1: pack rel->LDS + union plane, gemm<3>, last-arriver BN1+XW2 -
__global__ __launch_bounds__(512, 2) void k_g1(
    const int* __restrict__ rel, unsigned* __restrict__ UP,
    const unsigned short* __restrict__ XWS1, const float* __restrict__ b_first,
    float* __restrict__ H1, const float* __restrict__ w_block,
    unsigned short* __restrict__ XWS2, float* __restrict__ PP1,
    unsigned* __restrict__ cnt) {
  __shared__ __align__(16) char smem[49152];
  __shared__ unsigned lastf;
  const int bid = blockIdx.x, tid = threadIdx.x;
  const int b = bid & 7, it = bid >> 3;
  const int i0 = it * 64;
  {  // pack this tile's rel rows into LDS masks + emit union plane
    unsigned* mw3 = (unsigned*)smem;
    const int row = tid >> 3, seg = tid & 7;
    const int rsw = row & 31;
    const long base = ((long)b * NN + i0 + row) * NN + seg * 256;
#pragma unroll
    for (int w8 = 0; w8 < 8; ++w8) {
      const int w = seg * 8 + w8;
      const int4* rp = (const int4*)(rel + base + w8 * 32);
      unsigned m0 = 0, m1 = 0, m2 = 0;
#pragma unroll
      for (int c = 0; c < 8; ++c) {
        int4 v = rp[c];
        int vv[4] = {v.x, v.y, v.z, v.w};
#pragma unroll
        for (int q = 0; q < 4; ++q) {
          unsigned bit = 1u << (c * 4 + q);
          m0 |= (vv[q] == 1) ? bit : 0u;
          m1 |= (vv[q] == 2) ? bit : 0u;
          m2 |= (vv[q] == 3) ? bit : 0u;
        }
      }
      const int off = row * 64 + (w ^ rsw);
      mw3[off] = m0;
      mw3[4096 + off] = m1;
      mw3[8192 + off] = m2;
      UP[((long)b * NN + i0 + row) * 64 + w] = m0 | m1 | m2;
    }
  }
  __syncthreads();
  gemm_core<3, true, false>((unsigned*)smem, smem, XWS1, b_first, H1, nullptr,
                            b, it);
  if (last_arriver(&cnt[it], 8, &lastf))
    bnxw_all(smem, H1, w_block, XWS2, PP1, it);
}

// ---------- k_g2: union-plane gemm<1>, last-arriver BN2+XW3 ------------------
__global__ __launch_bounds__(512, 2) void k_g2(
    const unsigned* __restrict__ UP, const unsigned short* __restrict__ XWS2,
    const float* __restrict__ b_block, float* __restrict__ H2,
    const float* __restrict__ w_last, unsigned short* __restrict__ XWS3,
    float* __restrict__ PP2, unsigned* __restrict__ cnt) {
  __shared__ __align__(16) char smem[49152];
  __shared__ unsigned lastf;
  const int bid = blockIdx.x, tid = threadIdx.x;
  const int b = bid & 7, it = bid >> 3;
  const int i0 = it * 64;
  unsigned* mloc = (unsigned*)smem;
  for (int idx = tid; idx < 4096; idx += 512) {
    int row = idx >> 6, w = idx & 63;
    unsigned v = UP[((long)b * NN + i0 + row) * 64 + w];
    mloc[row * 64 + (w ^ (row & 31))] = v;
  }
  __syncthreads();
  gemm_core<1, true, false>(mloc, smem, XWS2, b_block, H2, nullptr, b, it);
  if (last_arriver(&cnt[it], 8, &lastf))
    bnxw_all(smem, H2, w_last, XWS3, PP2, it);
}

// ---------- k_g3: union-plane gemm<1> + pool3, last-arriver tail -------------
__global__ __launch_bounds__(512, 2) void k_g3(
    const unsigned* __restrict__ UP, const unsigned short* __restrict__ XWS3,
    const float* __restrict__ b_last, float* __restrict__ PART3,
    const float* __restrict__ PP1, const float* __restrict__ PP2,
    const float* __restrict__ w_map, const float* __restrict__ b_map,
    float* __restrict__ out, unsigned* __restrict__ cnt) {
  __shared__ __align__(16) char smem[49152];
  __shared__ unsigned lastf;
  const int bid = blockIdx.x, tid = threadIdx.x;
  const int b = bid & 7, it = bid >> 3;
  const int i0 = it * 64;
  unsigned* mloc = (unsigned*)smem;
  for (int idx = tid; idx < 4096; idx += 512) {
    int row = idx >> 6, w = idx & 63;
    unsigned v = UP[((long)b * NN + i0 + row) * 64 + w];
    mloc[row * 64 + (w ^ (row & 31))] = v;
  }
  __syncthreads();
  gemm_core<1, false, true>(mloc, smem, XWS3, b_last, nullptr, PART3, b, it);
  if (last_arriver(cnt, 256, &lastf)) {
    const int bb = tid >> 6, e = tid & 63;
    float m1 = -3.4e38f, m2 = -3.4e38f, m3 = -3.4e38f;
#pragma unroll
    for (int c = 0; c < 32; ++c) {
      m1 = fmaxf(m1, PP1[(long)c * 512 + tid]);
      m2 = fmaxf(m2, PP2[(long)c * 512 + tid]);
      m3 = fmaxf(m3, PART3[((long)bb * 32 + c) * 64 + e]);
    }
    out[bb * 192 + e] = m1;
    out[bb * 192 + 64 + e] = m2;
    out[bb * 192 + 128 + e] = m3;
    __syncthreads();
    float a = b_map[e];
    for (int k = 0; k < 192; ++k) a += out[bb * 192 + k] * w_map[k * 64 + e];
    out[1536 + bb * 64 + e] = a;
  }
}

extern "C" void kernel_launch(void* const* d_in, const int* in_sizes, int n_in,
                              void* d_out, int out_size, void* d_ws,
                              size_t ws_size, hipStream_t stream) {
  const float* x = (const float*)d_in[0];
  const int* rel = (const int*)d_in[1];
  // d_in[2] (adj) unread: adj == (rel > 0) == union of bit-planes
  const float* w_first = (const float*)d_in[3];
  const float* b_first = (const float*)d_in[4];
  const float* w_block = (const float*)d_in[5];
  const float* b_block = (const float*)d_in[6];
  const float* w_last = (const float*)d_in[7];
  const float* b_last = (const float*)d_in[8];
  const float* w_map = (const float*)d_in[9];
  const float* b_map = (const float*)d_in[10];
  float* out = (float*)d_out;

  char* ws = (char*)d_ws;
  const size_t MB = 1024 * 1024;
  unsigned short* XWS1 = (unsigned short*)(ws);           // 6 MiB
  unsigned short* XWS2 = (unsigned short*)(ws + 6 * MB);  // 2 MiB
  unsigned short* XWS3 = (unsigned short*)(ws + 8 * MB);  // 2 MiB
  float* H1 = (float*)(ws + 10 * MB);                     // 4 MiB
  float* H2 = (float*)(ws + 14 * MB);                     // 4 MiB
  unsigned* UP = (unsigned*)(ws + 18 * MB);               // 4 MiB union plane
  float* PP1 = (float*)(ws + 22 * MB);                    // 64 KiB
  float* PP2 = (float*)(ws + 23 * MB);                    // 64 KiB
  float* PART3 = (float*)(ws + 24 * MB);                  // 64 KiB
  unsigned* CNT = (unsigned*)(ws + 25 * MB);              // 512 B

  hipMemsetAsync((void*)CNT, 0, 512, stream);
  k_xw1<<<256, 512, 0, stream>>>(x, w_first, XWS1);
  k_g1<<<256, 512, 0, stream>>>(rel, UP, XWS1, b_first, H1, w_block, XWS2,
                                PP1, &CNT[0]);
  k_g2<<<256, 512, 0, stream>>>(UP, XWS2, b_block, H2, w_last, XWS3, PP2,
                                &CNT[32]);
  k_g3<<<256, 512, 0, stream>>>(UP, XWS3, b_last, PART3, PP1, PP2, w_map,
                                b_map, out, &CNT[64]);
}

// Round 10
// 356.188 us; speedup vs baseline: 2.2655x; 2.1100x over previous
//
#include <hip/hip_runtime.h>

// GcnEncoderGraph multi-kernel pipeline. B=8, N=2048, DIN=32, DH=DE=64, R=3.
// R10 = R7 (353us, best) + micro-fixes only. Structural journal:
//  - cg grid.sync ~97us/round (R4), hand-rolled spin ~70us/round (R8),
//    per-block device-scope fences (R9) all poison MI355X (non-coherent
//    per-XCD L2 -> fence = L2 writeback). Fence-free multi-kernel is optimal.
//  - TLP >> ILP at this size: gemm needs >=4 blocks/CU (R5/R6/R9 at 1-2
//    blocks/CU were 2-5x slower than R7's occupancy-rich shape).
// R10 changes: (a) mask->bf16 expand via u24 multiplies (17->10 VALU/frag;
// gemm loop was VALU-bound: ~408 VALU cyc vs 233 MFMA cyc per kblk);
// (b) pack also emits union plane; gemm2/3 stage from it (12->4 MiB reads).

#define NN 2048
#define PLANE_W 1048576L  // u32 words per bitplane: 8*2048*64

typedef short short8 __attribute__((ext_vector_type(8)));
typedef float floatx4 __attribute__((ext_vector_type(4)));

__device__ __forceinline__ unsigned short f2bf(float x) {
  unsigned u = __float_as_uint(x);
  u += 0x7FFFu + ((u >> 16) & 1u);
  return (unsigned short)(u >> 16);
}

// ---------- XW precompute (layer 1), swizzled to MFMA B-fragment order -------
__device__ void dev_xw_first(char* smemc, int u, int tid,
                             const float* __restrict__ x,
                             const float* __restrict__ w,
                             unsigned short* __restrict__ xws) {
  float* xs = (float*)smemc;                  // [64][33]
  float* wsh = (float*)(smemc + 64 * 33 * 4); // [32][64]
  const int jc = u & 31, b = (u >> 5) & 7, r = u >> 8;
  const int j0 = jc * 64;
  for (int idx = tid; idx < 64 * 32; idx += 256) {
    int row = idx >> 5, f = idx & 31;
    xs[row * 33 + f] = x[((long)b * NN + j0 + row) * 32 + f];
    wsh[idx] = w[r * 2048 + idx];  // [f][e]
  }
  __syncthreads();
  const int j = tid & 63, g = tid >> 6;
  const int k = j0 + j;
  const int kblk = k >> 5, kq = (k >> 3) & 3, kj = k & 7;
  unsigned short* dst =
      xws + (((long)(r * 8 + b) * 64 + kblk) * 4 + g) * 512 + kj;
  float xr[32];
#pragma unroll
  for (int f = 0; f < 32; ++f) xr[f] = xs[j * 33 + f];
#pragma unroll
  for (int ii = 0; ii < 16; ++ii) {
    float acc = 0.f;
#pragma unroll
    for (int f = 0; f < 32; ++f) acc += xr[f] * wsh[f * 64 + g * 16 + ii];
    dst[(kq * 16 + ii) * 8] = f2bf(acc);
  }
  __syncthreads();
}

// ---------- fused: pack relation -> 3 bitplanes + union plane; xw1 -----------
__global__ __launch_bounds__(256) void k_pack_xw1(const int* __restrict__ rel,
                                                  unsigned* __restrict__ planes,
                                                  unsigned* __restrict__ UP,
                                                  const float* __restrict__ x,
                                                  const float* __restrict__ w,
                                                  unsigned short* __restrict__ xws) {
  __shared__ __align__(16) char smem[16640];
  const int bid = blockIdx.x, tid = threadIdx.x;
  if (bid < 768) dev_xw_first(smem, bid, tid, x, w, xws);
  for (long t = (long)bid * 256 + tid; t < 1048576L; t += 4096L * 256) {
    int w32 = (int)(t & 63);
    long bi = t >> 6;  // b*2048 + i
    const int4* rp = (const int4*)(rel + bi * NN + w32 * 32);
    unsigned m0 = 0, m1 = 0, m2 = 0;
#pragma unroll
    for (int c = 0; c < 8; ++c) {
      int4 v = rp[c];
      int vv[4] = {v.x, v.y, v.z, v.w};
#pragma unroll
      for (int j = 0; j < 4; ++j) {
        unsigned b1 = 1u << (c * 4 + j);
        m0 |= (vv[j] == 1) ? b1 : 0u;
        m1 |= (vv[j] == 2) ? b1 : 0u;
        m2 |= (vv[j] == 3) ? b1 : 0u;
      }
    }
    long o = bi * 64 + w32;
    planes[o] = m0;
    planes[PLANE_W + o] = m1;
    planes[2 * PLANE_W + o] = m2;
    UP[o] = m0 | m1 | m2;
  }
}

// ---------- masked MFMA gemm: 8 waves interleave K, fused epilogue -----------
// grid 256: b = bid&7 (XCD affinity), it = bid>>3. Block 512 = 8 waves;
// wave w covers kblks == w (mod 8), all 64 rows (16 acc frags). Masks staged
// in 2 chunks of 32 kblks. Serial LDS combine -> wave 0 epilogue.
// NREL=3: planes = 3 bitplanes; NREL=1: planes = union plane.
template <int NREL, bool RELU, bool POOL3>
__global__ __launch_bounds__(512) void k_gemm8(
    const unsigned* __restrict__ planes, const unsigned short* __restrict__ xws,
    const float* __restrict__ bias, float* __restrict__ Hout,
    float* __restrict__ part3) {
  constexpr int SMEM = (NREL * 8448 > 16640) ? NREL * 8448 : 16640;
  __shared__ __align__(16) char smem[SMEM];
  unsigned* mw = (unsigned*)smem;  // [NREL][64 rows][33 words] per chunk
  floatx4* cb = (floatx4*)smem;    // 16 KB combine buffer (overlay)
  const int bid = blockIdx.x;
  const int b = bid & 7, it = bid >> 3;
  const int tid = threadIdx.x;
  const int wave = tid >> 6, lane = tid & 63;
  const int m = lane & 15, kq = lane >> 4;
  const int i0 = it * 64;

  floatx4 acc[4][4];  // [rowset][t]
#pragma unroll
  for (int rs = 0; rs < 4; ++rs)
#pragma unroll
    for (int t = 0; t < 4; ++t) acc[rs][t] = floatx4{0, 0, 0, 0};

  for (int chunk = 0; chunk < 2; ++chunk) {
    for (int idx = tid; idx < NREL * 2048; idx += 512) {
      int p = idx >> 11, rem = idx & 2047, row = rem >> 5, w = rem & 31;
      long g = ((long)b * NN + i0 + row) * 64 + chunk * 32 + w;
      unsigned v = (NREL == 3) ? planes[(long)p * PLANE_W + g] : planes[g];
      mw[(p * 64 + row) * 33 + w] = v;
    }
    __syncthreads();
#pragma unroll
    for (int j = 0; j < 4; ++j) {
      const int kk = j * 8 + wave;       // chunk-local kblk
      const int kblk = chunk * 32 + kk;  // global kblk
#pragma unroll
      for (int p = 0; p < NREL; ++p) {
        const unsigned short* bb =
            xws + ((long)(p * 8 + b) * 64 + kblk) * 2048 + lane * 8;
        short8 bf0 = *(const short8*)(bb);
        short8 bf1 = *(const short8*)(bb + 512);
        short8 bf2 = *(const short8*)(bb + 1024);
        short8 bf3 = *(const short8*)(bb + 1536);
#pragma unroll
        for (int rs = 0; rs < 4; ++rs) {
          unsigned word = mw[(p * 64 + rs * 16 + m) * 33 + kk];
          unsigned byte = (word >> (kq * 8)) & 0xffu;
          unsigned pp = byte | (byte << 15);
          union {
            unsigned uu[4];
            short8 s8;
          } fr;
          // bf16 1.0 (0x3F80) via u24 multiply: operands < 2^24 -> full-rate
          fr.uu[0] = (pp & 0x00010001u) * 0x3F80u;
          fr.uu[1] = (pp & 0x00040004u) * 0x0FE0u;
          fr.uu[2] = (pp & 0x00100010u) * 0x03F8u;
          fr.uu[3] = (pp & 0x00400040u) * 0x00FEu;
          acc[rs][0] = __builtin_amdgcn_mfma_f32_16x16x32_bf16(fr.s8, bf0,
                                                              acc[rs][0], 0, 0, 0);
          acc[rs][1] = __builtin_amdgcn_mfma_f32_16x16x32_bf16(fr.s8, bf1,
                                                              acc[rs][1], 0, 0, 0);
          acc[rs][2] = __builtin_amdgcn_mfma_f32_16x16x32_bf16(fr.s8, bf2,
                                                              acc[rs][2], 0, 0, 0);
          acc[rs][3] = __builtin_amdgcn_mfma_f32_16x16x32_bf16(fr.s8, bf3,
                                                              acc[rs][3], 0, 0, 0);
        }
      }
    }
    __syncthreads();
  }

  // serial combine: wave 7 writes, waves 6..1 add in turn, wave 0 in regs
  for (int k = 7; k >= 1; --k) {
    if (wave == k) {
      if (k == 7) {
#pragma unroll
        for (int rs = 0; rs < 4; ++rs)
#pragma unroll
          for (int t = 0; t < 4; ++t) cb[(rs * 4 + t) * 64 + lane] = acc[rs][t];
      } else {
#pragma unroll
        for (int rs = 0; rs < 4; ++rs)
#pragma unroll
          for (int t = 0; t < 4; ++t) {
            floatx4 v = cb[(rs * 4 + t) * 64 + lane];
            cb[(rs * 4 + t) * 64 + lane] = v + acc[rs][t];
          }
      }
    }
    __syncthreads();
  }
  if (wave == 0) {
#pragma unroll
    for (int rs = 0; rs < 4; ++rs)
#pragma unroll
      for (int t = 0; t < 4; ++t) acc[rs][t] += cb[(rs * 4 + t) * 64 + lane];
    float bv[4];
#pragma unroll
    for (int t = 0; t < 4; ++t) bv[t] = bias[t * 16 + m];
    float pmt[4] = {-3.4e38f, -3.4e38f, -3.4e38f, -3.4e38f};
#pragma unroll
    for (int rs = 0; rs < 4; ++rs) {
      float ss[4];
#pragma unroll
      for (int reg = 0; reg < 4; ++reg) {
#pragma unroll
        for (int t = 0; t < 4; ++t) acc[rs][t][reg] += bv[t];
        ss[reg] = acc[rs][0][reg] * acc[rs][0][reg] +
                  acc[rs][1][reg] * acc[rs][1][reg] +
                  acc[rs][2][reg] * acc[rs][2][reg] +
                  acc[rs][3][reg] * acc[rs][3][reg];
#pragma unroll
        for (int off = 1; off <= 8; off <<= 1)
          ss[reg] += __shfl_xor(ss[reg], off);
        ss[reg] = 1.0f / fmaxf(sqrtf(ss[reg]), 1e-12f);
      }
#pragma unroll
      for (int t = 0; t < 4; ++t) {
#pragma unroll
        for (int reg = 0; reg < 4; ++reg) {
          float o = acc[rs][t][reg] * ss[reg];
          if (RELU) o = fmaxf(o, 0.0f);
          if (POOL3)
            pmt[t] = fmaxf(pmt[t], o);
          else
            Hout[((long)b * NN + i0 + rs * 16 + kq * 4 + reg) * 64 + t * 16 + m] = o;
        }
      }
    }
    if (POOL3) {
#pragma unroll
      for (int t = 0; t < 4; ++t) {
        pmt[t] = fmaxf(pmt[t], __shfl_xor(pmt[t], 16));
        pmt[t] = fmaxf(pmt[t], __shfl_xor(pmt[t], 32));
      }
      if (kq == 0) {
#pragma unroll
        for (int t = 0; t < 4; ++t)
          part3[((long)b * 32 + it) * 64 + t * 16 + m] = pmt[t];
      }
    }
  }
}

// ---------- fused BN + xw_h (+pool partial from b==0 blocks) [R7-proven] -----
__global__ __launch_bounds__(256) void k_xwh_bn(const float* __restrict__ H,
                                                const float* __restrict__ w,
                                                unsigned short* __restrict__ xws,
                                                float* __restrict__ PP) {
  __shared__ float hs[64 * 65];
  __shared__ float wsh[64 * 64];
  __shared__ float sm[64], srs[64];
  const int bid = blockIdx.x, tid = threadIdx.x;
  const int jc = bid & 31, b = bid >> 5;
  const int j0 = jc * 64;
  {
    const int n = tid >> 2, q = tid & 3;
    float s1 = 0.f, s2 = 0.f;
#pragma unroll
    for (int bb = 0; bb < 8; ++bb) {
      const float4* hp =
          (const float4*)(H + ((long)bb * NN + j0 + n) * 64 + q * 16);
#pragma unroll
      for (int c = 0; c < 4; ++c) {
        float4 v = hp[c];
        s1 += v.x + v.y + v.z + v.w;
        s2 += v.x * v.x + v.y * v.y + v.z * v.z + v.w * v.w;
      }
    }
    s1 += __shfl_xor(s1, 1);
    s2 += __shfl_xor(s2, 1);
    s1 += __shfl_xor(s1, 2);
    s2 += __shfl_xor(s2, 2);
    if (q == 0) {
      float mean = s1 * (1.0f / 512.0f);
      float var = fmaxf(s2 * (1.0f / 512.0f) - mean * mean, 0.0f);
      sm[n] = mean;
      srs[n] = rsqrtf(var + 1e-5f);
    }
  }
  __syncthreads();
  for (int idx = tid; idx < 4096; idx += 256) {
    int row = idx >> 6, f = idx & 63;
    float v = H[((long)b * NN + j0 + row) * 64 + f];
    hs[row * 65 + f] = (v - sm[row]) * srs[row];
    wsh[idx] = w[idx];
  }
  __syncthreads();
  {
    const int j = tid & 63, g = tid >> 6;
    const int k = j0 + j;
    const int kblk = k >> 5, kq = (k >> 3) & 3, kj = k & 7;
    unsigned short* dst = xws + (((long)b * 64 + kblk) * 4 + g) * 512 + kj;
    float acc[16];
#pragma unroll
    for (int ii = 0; ii < 16; ++ii) acc[ii] = 0.f;
#pragma unroll
    for (int c = 0; c < 4; ++c) {
      float xr[16];
#pragma unroll
      for (int f = 0; f < 16; ++f) xr[f] = hs[j * 65 + c * 16 + f];
#pragma unroll
      for (int ii = 0; ii < 16; ++ii)
#pragma unroll
        for (int f = 0; f < 16; ++f)
          acc[ii] += xr[f] * wsh[(c * 16 + f) * 64 + g * 16 + ii];
    }
#pragma unroll
    for (int ii = 0; ii < 16; ++ii) dst[(kq * 16 + ii) * 8] = f2bf(acc[ii]);
  }
  if (b == 0) {
#pragma unroll
    for (int part = 0; part < 2; ++part) {
      const int col = part * 256 + tid;
      const int bb = col >> 6, e = col & 63;
      float mx = -3.4e38f;
      for (int n = 0; n < 64; ++n) {
        float v = H[((long)bb * NN + j0 + n) * 64 + e];
        mx = fmaxf(mx, (v - sm[n]) * srs[n]);
      }
      PP[(long)jc * 512 + col] = mx;
    }
  }
}

// ---------- tail: all pool finals + linear head ------------------------------
__global__ __launch_bounds__(512) void k_tail(const float* __restrict__ PP1,
                                              const float* __restrict__ PP2,
                                              const float* __restrict__ P3,
                                              float* __restrict__ out,
                                              const float* __restrict__ wmap,
                                              const float* __restrict__ bmap) {
  const int col = threadIdx.x;
  const int bb = col >> 6, e = col & 63;
  float m1 = -3.4e38f, m2 = -3.4e38f, m3 = -3.4e38f;
#pragma unroll
  for (int c = 0; c < 32; ++c) {
    m1 = fmaxf(m1, PP1[(long)c * 512 + col]);
    m2 = fmaxf(m2, PP2[(long)c * 512 + col]);
    m3 = fmaxf(m3, P3[((long)bb * 32 + c) * 64 + e]);
  }
  out[bb * 192 + e] = m1;
  out[bb * 192 + 64 + e] = m2;
  out[bb * 192 + 128 + e] = m3;
  __syncthreads();
  float acc = bmap[e];
  for (int k = 0; k < 192; ++k) acc += out[bb * 192 + k] * wmap[k * 64 + e];
  out[1536 + bb * 64 + e] = acc;
}

extern "C" void kernel_launch(void* const* d_in, const int* in_sizes, int n_in,
                              void* d_out, int out_size, void* d_ws,
                              size_t ws_size, hipStream_t stream) {
  const float* x = (const float*)d_in[0];
  const int* rel = (const int*)d_in[1];
  // d_in[2] (adj) unread: adj == (rel > 0) == union of bitplanes
  const float* w_first = (const float*)d_in[3];
  const float* b_first = (const float*)d_in[4];
  const float* w_block = (const float*)d_in[5];
  const float* b_block = (const float*)d_in[6];
  const float* w_last = (const float*)d_in[7];
  const float* b_last = (const float*)d_in[8];
  const float* w_map = (const float*)d_in[9];
  const float* b_map = (const float*)d_in[10];
  float* out = (float*)d_out;

  char* ws = (char*)d_ws;
  const size_t MB = 1024 * 1024;
  unsigned* PLANES = (unsigned*)(ws);                     // 12 MiB
  unsigned* UP = (unsigned*)(ws + 12 * MB);               // 4 MiB union plane
  unsigned short* XWS = (unsigned short*)(ws + 16 * MB);  // 6 MiB
  float* H = (float*)(ws + 24 * MB);                      // 4 MiB
  float* PP1 = (float*)(ws + 28 * MB);                    // 64 KiB
  float* PP2 = (float*)(ws + 29 * MB);                    // 64 KiB
  float* PART3 = (float*)(ws + 30 * MB);                  // 64 KiB

  // ---- pack bitplanes + union plane + XW(layer1) ----
  k_pack_xw1<<<4096, 256, 0, stream>>>(rel, PLANES, UP, x, w_first, XWS);
  // ---- layer 1 (fused bias+L2norm+relu) ----
  k_gemm8<3, true, false><<<256, 512, 0, stream>>>(PLANES, XWS, b_first, H,
                                                   nullptr);
  k_xwh_bn<<<256, 256, 0, stream>>>(H, w_block, XWS, PP1);
  // ---- layer 2 (union plane) ----
  k_gemm8<1, true, false><<<256, 512, 0, stream>>>(UP, XWS, b_block, H,
                                                   nullptr);
  k_xwh_bn<<<256, 256, 0, stream>>>(H, w_last, XWS, PP2);
  // ---- layer 3 (fused L2norm + pool3 partial) ----
  k_gemm8<1, false, true><<<256, 512, 0, stream>>>(UP, XWS, b_last, nullptr,
                                                   PART3);
  // ---- pool finals + head ----
  k_tail<<<1, 512, 0, stream>>>(PP1, PP2, PART3, out, w_map, b_map);
}